// Round 8
// baseline (411.924 us; speedup 1.0000x reference)
//
#include <hip/hip_runtime.h>
#include <hip/hip_bf16.h>

#define FIN 128
#define FOUT 64
#define TILE_ROWS 64       // rows per gemm block = 4 waves x 16

#define EPB 2048           // edges per scatter chunk (391 blocks)
#define NPB 32             // nodes per bucket (d >> 5)
#define NBUK_MAX 1600
#define CAP 768            // records per bucket region (mean 512, +11 sigma)
#define ACCS 68            // acc row stride (floats); 68=4x17 keeps 16B align,
                           // breaks bank alignment between node rows

// Workspace layout (bytes), ws >= 268 MB:
//   [0, 6,400,000)         support : N*64 bf16
//   OFF_CUR   +6,400       cur     : NBUK int (bucket fill counters)
//   OFF_OVFC  +64          ovfc    : 1 int (overflow count)
//   OFF_TMP   +9,830,400   tmp     : NBUK_MAX*CAP int2 regions {src|dloc<<16, ev}
//   OFF_OVF   +12,800,000  ovf     : E int4 {recx, recy, bucket, pad}
#define OFF_CUR   6400000
#define OFF_OVFC  6406400
#define OFF_TMP   6406464
#define OFF_OVF   16236864

typedef short bf16x8 __attribute__((ext_vector_type(8)));
typedef float f32x4  __attribute__((ext_vector_type(4)));

__device__ inline ushort f32_to_bf16_rne(float f) {
    unsigned u = __float_as_uint(f);
    u += 0x7FFFu + ((u >> 16) & 1u);
    return (ushort)(u >> 16);
}
__device__ inline float bf16_to_f32(ushort h) {
    return __uint_as_float((unsigned)h << 16);
}

// ---------------------------------------------------------------------------
// Fused, independent branches (no fences, no intra-kernel ordering):
//   blocks [0,GB):       MFMA gemm (W staged to LDS bf16, transposed+swizzled)
//   blocks [GB,GB+SBP):  scatter chunk -> fixed-CAP 32-node-bucket regions.
// Scatter: LDS hist of the chunk -> ONE returning global atomicAdd per
// present bucket (range reservation) -> place via LDS cursors.
// rec = {src | (d&31)<<16, ev_bits}   (src < 65536: N = 50000 ok)
// ---------------------------------------------------------------------------
union __align__(16) K1Sh {
    ushort wt[FOUT * FIN];                            // 16 KB (gemm)
    struct { int h[NBUK_MAX]; int c[NBUK_MAX]; } sc;  // 12.8 KB (scatter)
};

__global__ __launch_bounds__(256) void gemm_scatter_kernel(
    const float* __restrict__ x, const float* __restrict__ t,
    const float* __restrict__ W, ushort* __restrict__ support, int N,
    const int* __restrict__ src, const int* __restrict__ dst,
    const float* __restrict__ ev, int* __restrict__ cur,
    int2* __restrict__ tmp, int* __restrict__ ovfc, int4* __restrict__ ovf,
    int E, int SBP, int NBUK, int GB)
{
    __shared__ K1Sh sh;
    const int tid = threadIdx.x;

    if (blockIdx.x >= (unsigned)GB) {
        // ---- scatter branch ----
        const int chunk = blockIdx.x - GB;
        const int e0    = chunk * EPB;

        for (int i = tid; i < NBUK; i += 256) sh.sc.h[i] = 0;
        __syncthreads();

        // pass 1: local bucket counts
        for (int i = tid; i < EPB; i += 256) {
            int e = e0 + i;
            if (e < E) atomicAdd(&sh.sc.h[dst[e] >> 5], 1);
        }
        __syncthreads();

        // pass 2: reserve contiguous slices of bucket regions
        for (int j = tid; j < NBUK; j += 256) {
            int hj = sh.sc.h[j];
            if (hj) sh.sc.c[j] = atomicAdd(&cur[j], hj);
        }
        __syncthreads();

        // pass 3: place (dst re-read is L2-hot)
        for (int i = tid; i < EPB; i += 256) {
            int e = e0 + i;
            if (e < E) {
                int d = dst[e];
                int j = d >> 5;
                int s = atomicAdd(&sh.sc.c[j], 1);
                int2 rec = make_int2(src[e] | ((d & (NPB - 1)) << 16),
                                     __float_as_int(ev[e]));
                if (s < CAP) {
                    tmp[(size_t)j * CAP + s] = rec;
                } else {                 // never at this size; kept correct
                    int o = atomicAdd(ovfc, 1);
                    if (o < E) ovf[o] = make_int4(rec.x, rec.y, j, 0);
                }
            }
        }
        return;
    }

    // ---- MFMA gemm branch ----
    const int gb   = blockIdx.x;
    const int lane = tid & 63;
    const int w    = tid >> 6;          // wave 0..3
    const int ln   = lane & 15;
    const int q    = lane >> 4;         // quad 0..3
    const int rowb = gb * TILE_ROWS + w * 16;
    const int arow = rowb + ln;

    // Stage W -> LDS bf16, transposed WT[n][k]; 16B slot XOR-swizzled by n&7.
    // (ds_read_b128 64-lane = 1024B >= 8 bank-cycles floor; swizzle already
    // spreads across all 32 banks -- W path is at the b128 floor.)
    for (int idx = tid; idx < FIN * FOUT; idx += 256) {
        int k = idx >> 6;          // 0..127   (idx = k*FOUT + n)
        int n = idx & 63;          // 0..63
        sh.wt[n * FIN + (k ^ ((n & 7) << 3))] = f32_to_bf16_rne(W[idx]);
    }
    __syncthreads();

    f32x4 acc[4];
    #pragma unroll
    for (int nt = 0; nt < 4; ++nt)
        #pragma unroll
        for (int r = 0; r < 4; ++r) acc[nt][r] = 0.f;

    const bool aok = (arow < N);
    const float* xrow = &x[(size_t)arow * FIN];

    #pragma unroll
    for (int kc = 0; kc < 4; ++kc) {
        float xs[8];
        #pragma unroll
        for (int j = 0; j < 8; ++j) xs[j] = 0.f;
        if (aok) {
            float4 x0 = *(const float4*)&xrow[kc * 32 + q * 8];
            float4 x1 = *(const float4*)&xrow[kc * 32 + q * 8 + 4];
            xs[0] = x0.x; xs[1] = x0.y; xs[2] = x0.z; xs[3] = x0.w;
            xs[4] = x1.x; xs[5] = x1.y; xs[6] = x1.z; xs[7] = x1.w;
        }
        bf16x8 a;
        #pragma unroll
        for (int j = 0; j < 8; ++j) a[j] = (short)f32_to_bf16_rne(xs[j]);

        const int k0 = kc * 32 + q * 8;
        #pragma unroll
        for (int nt = 0; nt < 4; ++nt) {
            bf16x8 b = *(const bf16x8*)
                &sh.wt[(nt * 16 + ln) * FIN + (k0 ^ ((ln & 7) << 3))];
            acc[nt] = __builtin_amdgcn_mfma_f32_16x16x32_bf16(a, b, acc[nt], 0, 0, 0);
        }
    }

    // epilogue: D[m=q*4+reg][n=ln]; scale by t[row]; store bf16
    #pragma unroll
    for (int reg = 0; reg < 4; ++reg) {
        int r = rowb + q * 4 + reg;
        if (r < N) {
            float tv = t[r];
            #pragma unroll
            for (int nt = 0; nt < 4; ++nt)
                support[(size_t)r * FOUT + nt * 16 + ln] =
                    f32_to_bf16_rne(acc[nt][reg] * tv);
        }
    }
}

// ---------------------------------------------------------------------------
// bucket_gather v3: one block per 32-node bucket (1563 blocks). NO sort:
// direct LDS f32 accumulator acc[32][ACCS]. Single streaming pass over the
// bucket region: 16-lane group per record gathers the support row (uint2 per
// lane = full 128B row per record, read once) and ds_add_f32's into the
// node's acc row. 4-deep unroll = 16 gathers in flight per wave. Epilogue:
// coalesced float4 stores (+bias). Zero-degree nodes fall out (acc row = 0).
// ---------------------------------------------------------------------------
__global__ __launch_bounds__(256) void bucket_gather_kernel(
    const int* __restrict__ curg, const int2* __restrict__ tmp,
    const ushort* __restrict__ support, const float* __restrict__ bias,
    float* __restrict__ out, const int* __restrict__ ovfc,
    const int4* __restrict__ ovf, int E, int N, int NBUK)
{
    __shared__ float acc[NPB * ACCS];   // 8.7 KB
    __shared__ int novs;

    const int tid   = threadIdx.x;
    const int g     = tid >> 4;         // record group 0..15
    const int fl    = tid & 15;         // feature block (4 feats)
    const int B     = blockIdx.x;
    const int node0 = B * NPB;

    const int base   = B * CAP;
    const int tot    = curg[B];
    const int placed = (tot < CAP) ? tot : CAP;

    for (int i = tid; i < NPB * ACCS; i += 256) acc[i] = 0.f;
    __syncthreads();

    int i = g;
    // 4-deep unroll: 4 records per group in flight
    for (; i + 48 < placed; i += 64) {
        int2 r0 = tmp[base + i];
        int2 r1 = tmp[base + i + 16];
        int2 r2 = tmp[base + i + 32];
        int2 r3 = tmp[base + i + 48];
        uint2 u0 = *(const uint2*)&support[(size_t)(r0.x & 0xFFFF) * FOUT + fl * 4];
        uint2 u1 = *(const uint2*)&support[(size_t)(r1.x & 0xFFFF) * FOUT + fl * 4];
        uint2 u2 = *(const uint2*)&support[(size_t)(r2.x & 0xFFFF) * FOUT + fl * 4];
        uint2 u3 = *(const uint2*)&support[(size_t)(r3.x & 0xFFFF) * FOUT + fl * 4];
        float w0 = __int_as_float(r0.y), w1 = __int_as_float(r1.y);
        float w2 = __int_as_float(r2.y), w3 = __int_as_float(r3.y);
        float* a0 = &acc[((r0.x >> 16) & (NPB - 1)) * ACCS + fl * 4];
        float* a1 = &acc[((r1.x >> 16) & (NPB - 1)) * ACCS + fl * 4];
        float* a2 = &acc[((r2.x >> 16) & (NPB - 1)) * ACCS + fl * 4];
        float* a3 = &acc[((r3.x >> 16) & (NPB - 1)) * ACCS + fl * 4];
        atomicAdd(&a0[0], bf16_to_f32((ushort)(u0.x & 0xFFFFu)) * w0);
        atomicAdd(&a0[1], bf16_to_f32((ushort)(u0.x >> 16)) * w0);
        atomicAdd(&a0[2], bf16_to_f32((ushort)(u0.y & 0xFFFFu)) * w0);
        atomicAdd(&a0[3], bf16_to_f32((ushort)(u0.y >> 16)) * w0);
        atomicAdd(&a1[0], bf16_to_f32((ushort)(u1.x & 0xFFFFu)) * w1);
        atomicAdd(&a1[1], bf16_to_f32((ushort)(u1.x >> 16)) * w1);
        atomicAdd(&a1[2], bf16_to_f32((ushort)(u1.y & 0xFFFFu)) * w1);
        atomicAdd(&a1[3], bf16_to_f32((ushort)(u1.y >> 16)) * w1);
        atomicAdd(&a2[0], bf16_to_f32((ushort)(u2.x & 0xFFFFu)) * w2);
        atomicAdd(&a2[1], bf16_to_f32((ushort)(u2.x >> 16)) * w2);
        atomicAdd(&a2[2], bf16_to_f32((ushort)(u2.y & 0xFFFFu)) * w2);
        atomicAdd(&a2[3], bf16_to_f32((ushort)(u2.y >> 16)) * w2);
        atomicAdd(&a3[0], bf16_to_f32((ushort)(u3.x & 0xFFFFu)) * w3);
        atomicAdd(&a3[1], bf16_to_f32((ushort)(u3.x >> 16)) * w3);
        atomicAdd(&a3[2], bf16_to_f32((ushort)(u3.y & 0xFFFFu)) * w3);
        atomicAdd(&a3[3], bf16_to_f32((ushort)(u3.y >> 16)) * w3);
    }
    for (; i < placed; i += 16) {
        int2 r = tmp[base + i];
        uint2 u = *(const uint2*)&support[(size_t)(r.x & 0xFFFF) * FOUT + fl * 4];
        float wg = __int_as_float(r.y);
        float* a = &acc[((r.x >> 16) & (NPB - 1)) * ACCS + fl * 4];
        atomicAdd(&a[0], bf16_to_f32((ushort)(u.x & 0xFFFFu)) * wg);
        atomicAdd(&a[1], bf16_to_f32((ushort)(u.x >> 16)) * wg);
        atomicAdd(&a[2], bf16_to_f32((ushort)(u.y & 0xFFFFu)) * wg);
        atomicAdd(&a[3], bf16_to_f32((ushort)(u.y >> 16)) * wg);
    }
    __syncthreads();

    // epilogue: 8 threads per node, each writes 8 floats (+bias), coalesced
    {
        const int nl   = tid >> 3;        // 0..31
        const int f0   = (tid & 7) * 8;   // 0..56
        const int node = node0 + nl;
        if (node < N) {
            const float* a  = &acc[nl * ACCS + f0];
            float4 o0, o1;
            o0.x = a[0] + bias[f0 + 0]; o0.y = a[1] + bias[f0 + 1];
            o0.z = a[2] + bias[f0 + 2]; o0.w = a[3] + bias[f0 + 3];
            o1.x = a[4] + bias[f0 + 4]; o1.y = a[5] + bias[f0 + 5];
            o1.z = a[6] + bias[f0 + 6]; o1.w = a[7] + bias[f0 + 7];
            *(float4*)&out[(size_t)node * FOUT + f0]     = o0;
            *(float4*)&out[(size_t)node * FOUT + f0 + 4] = o1;
        }
    }

    // overflow tail: never taken at this size; kept for correctness.
    __syncthreads();
    if (tid == 0) novs = *ovfc;
    __syncthreads();
    int nov = novs;
    if (nov > 0) {
        if (nov > E) nov = E;
        __threadfence();
        const int w    = tid >> 6;
        const int lane = tid & 63;
        for (int k = w; k < nov; k += 4) {
            int4 r = ovf[k];
            if (r.z == B) {
                int node = node0 + ((r.x >> 16) & (NPB - 1));
                if (node < N) {
                    float v = bf16_to_f32(
                        support[(size_t)(r.x & 0xFFFF) * FOUT + lane]);
                    atomicAdd(&out[(size_t)node * FOUT + lane],
                              v * __int_as_float(r.y));
                }
            }
        }
    }
}

extern "C" void kernel_launch(void* const* d_in, const int* in_sizes, int n_in,
                              void* d_out, int out_size, void* d_ws, size_t ws_size,
                              hipStream_t stream) {
    const float* x    = (const float*)d_in[0];
    const float* t    = (const float*)d_in[1];
    const int*   src  = (const int*)d_in[2];
    const int*   dst  = (const int*)d_in[3];
    const float* ev   = (const float*)d_in[4];
    const float* W    = (const float*)d_in[5];
    const float* bias = (const float*)d_in[6];
    float* out = (float*)d_out;

    const int N = in_sizes[1];   // 50000
    const int E = in_sizes[2];   // 800000

    char*   ws      = (char*)d_ws;
    ushort* support = (ushort*)ws;
    int*    cur     = (int*)(ws + OFF_CUR);
    int*    ovfc    = (int*)(ws + OFF_OVFC);
    int2*   tmp     = (int2*)(ws + OFF_TMP);
    int4*   ovf     = (int4*)(ws + OFF_OVF);

    const int GB   = (N + TILE_ROWS - 1) / TILE_ROWS;       // 782
    const int SBP  = (E + EPB - 1) / EPB;                   // 391
    const int NBUK = (N + NPB - 1) / NPB;                   // 1563

    // zero bucket cursors + overflow count (6.5 KB, graph-capturable)
    hipMemsetAsync(ws + OFF_CUR, 0, OFF_TMP - OFF_CUR, stream);

    // 1) fused independent branches: MFMA gemm || bucket-region scatter
    gemm_scatter_kernel<<<GB + SBP, 256, 0, stream>>>(
        x, t, W, support, N, src, dst, ev, cur, tmp, ovfc, ovf,
        E, SBP, NBUK, GB);

    // 2) per-bucket direct LDS-atomic accumulate -> out (+bias)
    bucket_gather_kernel<<<NBUK, 256, 0, stream>>>(
        cur, tmp, support, bias, out, ovfc, ovf, E, N, NBUK);
}

// Round 9
// 137.897 us; speedup vs baseline: 2.9872x; 2.9872x over previous
//
#include <hip/hip_runtime.h>
#include <hip/hip_bf16.h>

#define FIN 128
#define FOUT 64
#define TILE_ROWS 128      // rows per gemm block = 4 waves x 2 x 16

#define EPB 2048           // edges per scatter chunk (391 blocks)
#define NPB 32             // nodes per bucket (d >> 5)
#define NBUK_MAX 1600
#define CAP 768            // records per bucket region (mean 512, +11 sigma)

// Workspace layout (bytes), ws >= 268 MB:
//   [0, 6,400,000)         support : N*64 bf16
//   OFF_CUR   +6,400       cur     : NBUK int (bucket fill counters)
//   OFF_OVFC  +64          ovfc    : 1 int (overflow count)
//   OFF_TMP   +9,830,400   tmp     : NBUK_MAX*CAP int2 regions {src|dloc<<16, ev}
//   OFF_OVF   +12,800,000  ovf     : E int4 {recx, recy, bucket, pad}
#define OFF_CUR   6400000
#define OFF_OVFC  6406400
#define OFF_TMP   6406464
#define OFF_OVF   16236864

typedef short bf16x8 __attribute__((ext_vector_type(8)));
typedef float f32x4  __attribute__((ext_vector_type(4)));

__device__ inline ushort f32_to_bf16_rne(float f) {
    unsigned u = __float_as_uint(f);
    u += 0x7FFFu + ((u >> 16) & 1u);
    return (ushort)(u >> 16);
}
__device__ inline float bf16_to_f32(ushort h) {
    return __uint_as_float((unsigned)h << 16);
}

// ---------------------------------------------------------------------------
// Fused, independent branches (no fences, no intra-kernel ordering):
//   blocks [0,SBP):      scatter chunk -> fixed-CAP 32-node-bucket regions
//                        (FIRST so latency-bound work overlaps GEMM from t=0)
//   blocks [SBP,..):     MFMA gemm, 128-row tiles (W staged once per block,
//                        B-fragments reused across both 16-row sub-tiles).
// rec = {src | (d&31)<<16, ev_bits}   (src < 65536: N = 50000 ok)
// NOTE (R8 lesson): never use fp LDS atomics on gfx950 -- observed 308us
// stall (VALUBusy 1.6%) from the RMW serialization path.
// ---------------------------------------------------------------------------
union __align__(16) K1Sh {
    ushort wt[FOUT * FIN];                            // 16 KB (gemm)
    struct { int h[NBUK_MAX]; int c[NBUK_MAX]; } sc;  // 12.8 KB (scatter)
};

__global__ __launch_bounds__(256) void gemm_scatter_kernel(
    const float* __restrict__ x, const float* __restrict__ t,
    const float* __restrict__ W, ushort* __restrict__ support, int N,
    const int* __restrict__ src, const int* __restrict__ dst,
    const float* __restrict__ ev, int* __restrict__ cur,
    int2* __restrict__ tmp, int* __restrict__ ovfc, int4* __restrict__ ovf,
    int E, int SBP, int NBUK, int GB)
{
    __shared__ K1Sh sh;
    const int tid = threadIdx.x;

    if (blockIdx.x < (unsigned)SBP) {
        // ---- scatter branch ----
        const int chunk = blockIdx.x;
        const int e0    = chunk * EPB;

        for (int i = tid; i < NBUK; i += 256) sh.sc.h[i] = 0;
        __syncthreads();

        // pass 1: local bucket counts
        for (int i = tid; i < EPB; i += 256) {
            int e = e0 + i;
            if (e < E) atomicAdd(&sh.sc.h[dst[e] >> 5], 1);
        }
        __syncthreads();

        // pass 2: reserve contiguous slices of bucket regions
        for (int j = tid; j < NBUK; j += 256) {
            int hj = sh.sc.h[j];
            if (hj) sh.sc.c[j] = atomicAdd(&cur[j], hj);
        }
        __syncthreads();

        // pass 3: place (dst re-read is L2-hot)
        for (int i = tid; i < EPB; i += 256) {
            int e = e0 + i;
            if (e < E) {
                int d = dst[e];
                int j = d >> 5;
                int s = atomicAdd(&sh.sc.c[j], 1);
                int2 rec = make_int2(src[e] | ((d & (NPB - 1)) << 16),
                                     __float_as_int(ev[e]));
                if (s < CAP) {
                    tmp[(size_t)j * CAP + s] = rec;
                } else {                 // never at this size; kept correct
                    int o = atomicAdd(ovfc, 1);
                    if (o < E) ovf[o] = make_int4(rec.x, rec.y, j, 0);
                }
            }
        }
        return;
    }

    // ---- MFMA gemm branch: 128-row tile, 2 sub-tiles of 16 rows per wave ----
    const int gb   = blockIdx.x - SBP;
    const int lane = tid & 63;
    const int w    = tid >> 6;          // wave 0..3
    const int ln   = lane & 15;
    const int q    = lane >> 4;         // quad 0..3
    const int rowb = gb * TILE_ROWS + w * 32;

    // Stage W -> LDS bf16, transposed WT[n][k]; 16B slot XOR-swizzled by n&7.
    // Vectorized: float4 loads (8 x 16B per thread).
    for (int it = 0; it < 8; ++it) {
        int eidx = (tid + it * 256) * 4;        // element index, 4 consecutive n
        float4 wv = *(const float4*)&W[eidx];
        int k  = eidx >> 6;                     // 0..127
        int n0 = eidx & 63;                     // 0,4,..,60
        sh.wt[(n0 + 0) * FIN + (k ^ (((n0 + 0) & 7) << 3))] = f32_to_bf16_rne(wv.x);
        sh.wt[(n0 + 1) * FIN + (k ^ (((n0 + 1) & 7) << 3))] = f32_to_bf16_rne(wv.y);
        sh.wt[(n0 + 2) * FIN + (k ^ (((n0 + 2) & 7) << 3))] = f32_to_bf16_rne(wv.z);
        sh.wt[(n0 + 3) * FIN + (k ^ (((n0 + 3) & 7) << 3))] = f32_to_bf16_rne(wv.w);
    }
    __syncthreads();

    f32x4 acc[2][4];
    #pragma unroll
    for (int mt = 0; mt < 2; ++mt)
        #pragma unroll
        for (int nt = 0; nt < 4; ++nt)
            #pragma unroll
            for (int r = 0; r < 4; ++r) acc[mt][nt][r] = 0.f;

    const int arow0 = rowb + ln;
    const int arow1 = rowb + 16 + ln;
    const bool aok0 = (arow0 < N);
    const bool aok1 = (arow1 < N);
    const float* xrow0 = &x[(size_t)arow0 * FIN];
    const float* xrow1 = &x[(size_t)arow1 * FIN];

    #pragma unroll
    for (int kc = 0; kc < 4; ++kc) {
        const int k0 = kc * 32 + q * 8;
        bf16x8 a0, a1;
        {
            float xs[8];
            #pragma unroll
            for (int j = 0; j < 8; ++j) xs[j] = 0.f;
            if (aok0) {
                float4 v0 = *(const float4*)&xrow0[k0];
                float4 v1 = *(const float4*)&xrow0[k0 + 4];
                xs[0] = v0.x; xs[1] = v0.y; xs[2] = v0.z; xs[3] = v0.w;
                xs[4] = v1.x; xs[5] = v1.y; xs[6] = v1.z; xs[7] = v1.w;
            }
            #pragma unroll
            for (int j = 0; j < 8; ++j) a0[j] = (short)f32_to_bf16_rne(xs[j]);
        }
        {
            float xs[8];
            #pragma unroll
            for (int j = 0; j < 8; ++j) xs[j] = 0.f;
            if (aok1) {
                float4 v0 = *(const float4*)&xrow1[k0];
                float4 v1 = *(const float4*)&xrow1[k0 + 4];
                xs[0] = v0.x; xs[1] = v0.y; xs[2] = v0.z; xs[3] = v0.w;
                xs[4] = v1.x; xs[5] = v1.y; xs[6] = v1.z; xs[7] = v1.w;
            }
            #pragma unroll
            for (int j = 0; j < 8; ++j) a1[j] = (short)f32_to_bf16_rne(xs[j]);
        }
        #pragma unroll
        for (int nt = 0; nt < 4; ++nt) {
            bf16x8 b = *(const bf16x8*)
                &sh.wt[(nt * 16 + ln) * FIN + (k0 ^ ((ln & 7) << 3))];
            acc[0][nt] = __builtin_amdgcn_mfma_f32_16x16x32_bf16(a0, b, acc[0][nt], 0, 0, 0);
            acc[1][nt] = __builtin_amdgcn_mfma_f32_16x16x32_bf16(a1, b, acc[1][nt], 0, 0, 0);
        }
    }

    // epilogue: D[m=q*4+reg][n=ln]; scale by t[row]; store bf16
    #pragma unroll
    for (int mt = 0; mt < 2; ++mt) {
        #pragma unroll
        for (int reg = 0; reg < 4; ++reg) {
            int r = rowb + mt * 16 + q * 4 + reg;
            if (r < N) {
                float tv = t[r];
                #pragma unroll
                for (int nt = 0; nt < 4; ++nt)
                    support[(size_t)r * FOUT + nt * 16 + ln] =
                        f32_to_bf16_rne(acc[mt][nt][reg] * tv);
            }
        }
    }
}

// ---------------------------------------------------------------------------
// bucket_gather (R7 walk, direct-place sort): one block per 32-node bucket.
// pass A: coalesced region read -> LDS int counts; wave-0 shfl scan;
// pass B: re-read region (L2-hot) -> place directly into sorted[] (no raw[]).
// walk v2: wave w owns 8 nodes; 4 record groups x 16 feature-lanes; 16
// support gathers in flight per wave; shfl_xor cross-group reduce; coalesced
// float4 store (+bias). Zero-count nodes fall out naturally.
// ---------------------------------------------------------------------------
__global__ __launch_bounds__(256) void bucket_gather_kernel(
    const int* __restrict__ curg, const int2* __restrict__ tmp,
    const ushort* __restrict__ support, const float* __restrict__ bias,
    float* __restrict__ out, const int* __restrict__ ovfc,
    const int4* __restrict__ ovf, int E, int N, int NBUK)
{
    __shared__ int2 sorted[CAP];        // 6 KB
    __shared__ int  cnt[NPB];
    __shared__ int  starts[NPB + 1];
    __shared__ int  cur[NPB];
    __shared__ int  novs;

    const int tid   = threadIdx.x;
    const int w     = tid >> 6;
    const int lane  = tid & 63;
    const int B     = blockIdx.x;
    const int node0 = B * NPB;

    const int base   = B * CAP;
    const int tot    = curg[B];
    const int placed = (tot < CAP) ? tot : CAP;

    if (tid < NPB) cnt[tid] = 0;
    __syncthreads();

    // pass A: coalesced read, count only
    for (int i = tid; i < placed; i += 256) {
        int2 r = tmp[base + i];
        atomicAdd(&cnt[(r.x >> 16) & (NPB - 1)], 1);
    }
    __syncthreads();

    // wave-0 shfl scan over 32 counters
    if (tid < 64) {
        int v   = (tid < NPB) ? cnt[tid] : 0;
        int val = v;
        #pragma unroll
        for (int d = 1; d < NPB; d <<= 1) {
            int n = __shfl_up(val, d);
            if (tid >= d) val += n;
        }
        if (tid < NPB) {
            starts[tid] = val - v;
            cur[tid]    = val - v;
        }
        if (tid == 0) starts[NPB] = placed;
    }
    __syncthreads();

    // pass B: re-read (L2-hot) and place directly
    for (int i = tid; i < placed; i += 256) {
        int2 r  = tmp[base + i];
        int pos = atomicAdd(&cur[(r.x >> 16) & (NPB - 1)], 1);
        sorted[pos] = r;
    }
    __syncthreads();

    // ---- walk v2: wave w owns nodes [w*8, (w+1)*8) ----
    const int fl = lane & 15;           // feature block 0..15 (4 feats each)
    const int g  = lane >> 4;           // record group 0..3
    const float4 bv4 = *(const float4*)&bias[fl * 4];

    for (int nn = 0; nn < 8; ++nn) {
        const int nl = w * 8 + nn;      // node-local index 0..31
        const int rb = starts[nl];
        const int re = starts[nl + 1];

        float a0 = 0.f, a1 = 0.f, a2 = 0.f, a3 = 0.f;
        for (int i = rb + g; i < re; i += 4) {
            int2 r = sorted[i];                           // broadcast in group
            uint2 u = *(const uint2*)
                &support[(size_t)(r.x & 0xFFFF) * FOUT + fl * 4];
            float wg = __int_as_float(r.y);
            a0 += bf16_to_f32((ushort)(u.x & 0xFFFFu)) * wg;
            a1 += bf16_to_f32((ushort)(u.x >> 16)) * wg;
            a2 += bf16_to_f32((ushort)(u.y & 0xFFFFu)) * wg;
            a3 += bf16_to_f32((ushort)(u.y >> 16)) * wg;
        }
        // reduce across the 4 record groups (lanes fl, fl+16, fl+32, fl+48)
        #pragma unroll
        for (int d = 16; d < 64; d <<= 1) {
            a0 += __shfl_xor(a0, d);
            a1 += __shfl_xor(a1, d);
            a2 += __shfl_xor(a2, d);
            a3 += __shfl_xor(a3, d);
        }
        const int node = node0 + nl;
        if (g == 0 && node < N) {
            float4 o;
            o.x = a0 + bv4.x; o.y = a1 + bv4.y;
            o.z = a2 + bv4.z; o.w = a3 + bv4.w;
            *(float4*)&out[(size_t)node * FOUT + fl * 4] = o;
        }
    }

    // overflow tail: never taken at this size; kept for correctness.
    __syncthreads();
    if (tid == 0) novs = *ovfc;
    __syncthreads();
    int nov = novs;
    if (nov > 0) {
        if (nov > E) nov = E;
        __threadfence();
        for (int k = w; k < nov; k += 4) {
            int4 r = ovf[k];
            if (r.z == B) {
                int node = node0 + ((r.x >> 16) & (NPB - 1));
                if (node < N) {
                    float v = bf16_to_f32(
                        support[(size_t)(r.x & 0xFFFF) * FOUT + lane]);
                    atomicAdd(&out[(size_t)node * FOUT + lane],
                              v * __int_as_float(r.y));
                }
            }
        }
    }
}

extern "C" void kernel_launch(void* const* d_in, const int* in_sizes, int n_in,
                              void* d_out, int out_size, void* d_ws, size_t ws_size,
                              hipStream_t stream) {
    const float* x    = (const float*)d_in[0];
    const float* t    = (const float*)d_in[1];
    const int*   src  = (const int*)d_in[2];
    const int*   dst  = (const int*)d_in[3];
    const float* ev   = (const float*)d_in[4];
    const float* W    = (const float*)d_in[5];
    const float* bias = (const float*)d_in[6];
    float* out = (float*)d_out;

    const int N = in_sizes[1];   // 50000
    const int E = in_sizes[2];   // 800000

    char*   ws      = (char*)d_ws;
    ushort* support = (ushort*)ws;
    int*    cur     = (int*)(ws + OFF_CUR);
    int*    ovfc    = (int*)(ws + OFF_OVFC);
    int2*   tmp     = (int2*)(ws + OFF_TMP);
    int4*   ovf     = (int4*)(ws + OFF_OVF);

    const int GB   = (N + TILE_ROWS - 1) / TILE_ROWS;       // 391
    const int SBP  = (E + EPB - 1) / EPB;                   // 391
    const int NBUK = (N + NPB - 1) / NPB;                   // 1563

    // zero bucket cursors + overflow count (6.5 KB, graph-capturable)
    hipMemsetAsync(ws + OFF_CUR, 0, OFF_TMP - OFF_CUR, stream);

    // 1) fused independent branches: bucket-region scatter (first) || gemm
    gemm_scatter_kernel<<<SBP + GB, 256, 0, stream>>>(
        x, t, W, support, N, src, dst, ev, cur, tmp, ovfc, ovf,
        E, SBP, NBUK, GB);

    // 2) per-bucket direct-place sort + 4-wide record walk -> out (+bias)
    bucket_gather_kernel<<<NBUK, 256, 0, stream>>>(
        cur, tmp, support, bias, out, ovfc, ovf, E, N, NBUK);
}

// Round 10
// 128.400 us; speedup vs baseline: 3.2081x; 1.0740x over previous
//
#include <hip/hip_runtime.h>
#include <hip/hip_bf16.h>

#define FIN 128
#define FOUT 64
#define TILE_ROWS 64       // rows per gemm block = 4 waves x 16

#define EPB 2048           // edges per scatter chunk (391 blocks)
#define NPB 32             // nodes per bucket (d >> 5)
#define NBUK_MAX 1600
#define CAP 768            // records per bucket region (mean 512, +11 sigma)

// Workspace layout (bytes), ws >= 268 MB:
//   [0, 6,400,000)         support : N*64 bf16
//   OFF_CUR   +6,400       cur     : NBUK int (bucket fill counters)
//   OFF_OVFC  +64          ovfc    : 1 int (overflow count)
//   OFF_TMP   +9,830,400   tmp     : NBUK_MAX*CAP int2 regions {src|dloc<<16, ev}
//   OFF_OVF   +12,800,000  ovf     : E int4 {recx, recy, bucket, pad}
#define OFF_CUR   6400000
#define OFF_OVFC  6406400
#define OFF_TMP   6406464
#define OFF_OVF   16236864

typedef short bf16x8 __attribute__((ext_vector_type(8)));
typedef float f32x4  __attribute__((ext_vector_type(4)));

__device__ inline ushort f32_to_bf16_rne(float f) {
    unsigned u = __float_as_uint(f);
    u += 0x7FFFu + ((u >> 16) & 1u);
    return (ushort)(u >> 16);
}
__device__ inline float bf16_to_f32(ushort h) {
    return __uint_as_float((unsigned)h << 16);
}

// ---------------------------------------------------------------------------
// Fused, independent branches (no fences, no intra-kernel ordering):
//   blocks [0,GB):       MFMA gemm (W staged to LDS bf16, transposed+swizzled)
//   blocks [GB,GB+SBP):  scatter chunk -> fixed-CAP 32-node-bucket regions.
// Scatter: LDS hist of the chunk -> ONE returning global atomicAdd per
// present bucket (range reservation) -> place via LDS cursors.
// rec = {src | (d&31)<<16, ev_bits}   (src < 65536: N = 50000 ok)
// NOTE (R8 lesson): never use fp LDS atomics on gfx950 (308us RMW stall).
// NOTE (R9 lesson): TILE_ROWS=128 starves GEMM wave count (391 blocks ->
// 1.5 waves/SIMD tail); keep 64.
// ---------------------------------------------------------------------------
union __align__(16) K1Sh {
    ushort wt[FOUT * FIN];                            // 16 KB (gemm)
    struct { int h[NBUK_MAX]; int c[NBUK_MAX]; } sc;  // 12.8 KB (scatter)
};

__global__ __launch_bounds__(256) void gemm_scatter_kernel(
    const float* __restrict__ x, const float* __restrict__ t,
    const float* __restrict__ W, ushort* __restrict__ support, int N,
    const int* __restrict__ src, const int* __restrict__ dst,
    const float* __restrict__ ev, int* __restrict__ cur,
    int2* __restrict__ tmp, int* __restrict__ ovfc, int4* __restrict__ ovf,
    int E, int SBP, int NBUK, int GB)
{
    __shared__ K1Sh sh;
    const int tid = threadIdx.x;

    if (blockIdx.x >= (unsigned)GB) {
        // ---- scatter branch ----
        const int chunk = blockIdx.x - GB;
        const int e0    = chunk * EPB;

        for (int i = tid; i < NBUK; i += 256) sh.sc.h[i] = 0;
        __syncthreads();

        // pass 1: local bucket counts
        for (int i = tid; i < EPB; i += 256) {
            int e = e0 + i;
            if (e < E) atomicAdd(&sh.sc.h[dst[e] >> 5], 1);
        }
        __syncthreads();

        // pass 2: reserve contiguous slices of bucket regions
        for (int j = tid; j < NBUK; j += 256) {
            int hj = sh.sc.h[j];
            if (hj) sh.sc.c[j] = atomicAdd(&cur[j], hj);
        }
        __syncthreads();

        // pass 3: place (dst re-read is L2-hot)
        for (int i = tid; i < EPB; i += 256) {
            int e = e0 + i;
            if (e < E) {
                int d = dst[e];
                int j = d >> 5;
                int s = atomicAdd(&sh.sc.c[j], 1);
                int2 rec = make_int2(src[e] | ((d & (NPB - 1)) << 16),
                                     __float_as_int(ev[e]));
                if (s < CAP) {
                    tmp[(size_t)j * CAP + s] = rec;
                } else {                 // never at this size; kept correct
                    int o = atomicAdd(ovfc, 1);
                    if (o < E) ovf[o] = make_int4(rec.x, rec.y, j, 0);
                }
            }
        }
        return;
    }

    // ---- MFMA gemm branch ----
    const int gb   = blockIdx.x;
    const int lane = tid & 63;
    const int w    = tid >> 6;          // wave 0..3
    const int ln   = lane & 15;
    const int q    = lane >> 4;         // quad 0..3
    const int rowb = gb * TILE_ROWS + w * 16;
    const int arow = rowb + ln;

    // Stage W -> LDS bf16, transposed WT[n][k]; 16B slot XOR-swizzled by n&7.
    // Vectorized: 8 x float4 loads per thread (vs 32 scalar).
    #pragma unroll
    for (int it = 0; it < 8; ++it) {
        int eidx = (tid + it * 256) * 4;        // element index; 4 consecutive n
        float4 wv = *(const float4*)&W[eidx];
        int k  = eidx >> 6;                     // 0..127
        int n0 = eidx & 63;                     // 0,4,..,60
        sh.wt[(n0 + 0) * FIN + (k ^ (((n0 + 0) & 7) << 3))] = f32_to_bf16_rne(wv.x);
        sh.wt[(n0 + 1) * FIN + (k ^ (((n0 + 1) & 7) << 3))] = f32_to_bf16_rne(wv.y);
        sh.wt[(n0 + 2) * FIN + (k ^ (((n0 + 2) & 7) << 3))] = f32_to_bf16_rne(wv.z);
        sh.wt[(n0 + 3) * FIN + (k ^ (((n0 + 3) & 7) << 3))] = f32_to_bf16_rne(wv.w);
    }
    __syncthreads();

    f32x4 acc[4];
    #pragma unroll
    for (int nt = 0; nt < 4; ++nt)
        #pragma unroll
        for (int r = 0; r < 4; ++r) acc[nt][r] = 0.f;

    const bool aok = (arow < N);
    const float* xrow = &x[(size_t)arow * FIN];

    #pragma unroll
    for (int kc = 0; kc < 4; ++kc) {
        float xs[8];
        #pragma unroll
        for (int j = 0; j < 8; ++j) xs[j] = 0.f;
        if (aok) {
            float4 x0 = *(const float4*)&xrow[kc * 32 + q * 8];
            float4 x1 = *(const float4*)&xrow[kc * 32 + q * 8 + 4];
            xs[0] = x0.x; xs[1] = x0.y; xs[2] = x0.z; xs[3] = x0.w;
            xs[4] = x1.x; xs[5] = x1.y; xs[6] = x1.z; xs[7] = x1.w;
        }
        bf16x8 a;
        #pragma unroll
        for (int j = 0; j < 8; ++j) a[j] = (short)f32_to_bf16_rne(xs[j]);

        const int k0 = kc * 32 + q * 8;
        #pragma unroll
        for (int nt = 0; nt < 4; ++nt) {
            bf16x8 b = *(const bf16x8*)
                &sh.wt[(nt * 16 + ln) * FIN + (k0 ^ ((ln & 7) << 3))];
            acc[nt] = __builtin_amdgcn_mfma_f32_16x16x32_bf16(a, b, acc[nt], 0, 0, 0);
        }
    }

    // epilogue: D[m=q*4+reg][n=ln]; scale by t[row]; store bf16
    #pragma unroll
    for (int reg = 0; reg < 4; ++reg) {
        int r = rowb + q * 4 + reg;
        if (r < N) {
            float tv = t[r];
            #pragma unroll
            for (int nt = 0; nt < 4; ++nt)
                support[(size_t)r * FOUT + nt * 16 + ln] =
                    f32_to_bf16_rne(acc[nt][reg] * tv);
        }
    }
}

// ---------------------------------------------------------------------------
// bucket_gather: one block per 32-node bucket (1563 blocks). R7 sort
// (raw[] stage + count -> wave-0 shfl scan -> reorder), then walk v3:
// each 16-lane group owns 2 WHOLE nodes (no cross-group reduce, no
// divergent store): group accumulates the node's full 64-feature row
// (4 floats/lane), records 4-deep unrolled (16 gathers in flight/wave),
// then 16 lanes store float4 = 256B contiguous. Zero-count nodes fall
// out naturally (empty loop -> bias row). No float atomics normally.
// ---------------------------------------------------------------------------
__global__ __launch_bounds__(256) void bucket_gather_kernel(
    const int* __restrict__ curg, const int2* __restrict__ tmp,
    const ushort* __restrict__ support, const float* __restrict__ bias,
    float* __restrict__ out, const int* __restrict__ ovfc,
    const int4* __restrict__ ovf, int E, int N, int NBUK)
{
    __shared__ int2 raw[CAP];           // 6 KB
    __shared__ int2 sorted[CAP];        // 6 KB
    __shared__ int  cnt[NPB];
    __shared__ int  starts[NPB + 1];
    __shared__ int  cur[NPB];
    __shared__ int  novs;

    const int tid   = threadIdx.x;
    const int w     = tid >> 6;
    const int lane  = tid & 63;
    const int B     = blockIdx.x;
    const int node0 = B * NPB;

    const int base   = B * CAP;
    const int tot    = curg[B];
    const int placed = (tot < CAP) ? tot : CAP;

    if (tid < NPB) cnt[tid] = 0;
    __syncthreads();

    // single global read of the region: stage + count
    for (int i = tid; i < placed; i += 256) {
        int2 r = tmp[base + i];
        raw[i] = r;
        atomicAdd(&cnt[(r.x >> 16) & (NPB - 1)], 1);
    }
    __syncthreads();

    // wave-0 shfl scan over 32 counters
    if (tid < 64) {
        int v   = (tid < NPB) ? cnt[tid] : 0;
        int val = v;
        #pragma unroll
        for (int d = 1; d < NPB; d <<= 1) {
            int n = __shfl_up(val, d);
            if (tid >= d) val += n;
        }
        if (tid < NPB) {
            starts[tid] = val - v;
            cur[tid]    = val - v;
        }
        if (tid == 0) starts[NPB] = placed;
    }
    __syncthreads();

    // reorder LDS -> LDS
    for (int i = tid; i < placed; i += 256) {
        int2 r  = raw[i];
        int pos = atomicAdd(&cur[(r.x >> 16) & (NPB - 1)], 1);
        sorted[pos] = r;
    }
    __syncthreads();

    // ---- walk v3: group g of wave w owns nodes w*8 + g*2 + {0,1} ----
    const int fl = lane & 15;           // feature block 0..15 (4 feats each)
    const int g  = lane >> 4;           // group 0..3
    const float4 bv4 = *(const float4*)&bias[fl * 4];

    #pragma unroll
    for (int sub = 0; sub < 2; ++sub) {
        const int nl = w * 8 + g * 2 + sub;   // node-local 0..31
        const int rb = starts[nl];
        const int re = starts[nl + 1];

        float a0 = 0.f, a1 = 0.f, a2 = 0.f, a3 = 0.f;
        int i = rb;
        for (; i + 4 <= re; i += 4) {          // 4 records in flight
            int2 r0 = sorted[i],     r1 = sorted[i + 1];
            int2 r2 = sorted[i + 2], r3 = sorted[i + 3];
            uint2 u0 = *(const uint2*)&support[(size_t)(r0.x & 0xFFFF) * FOUT + fl * 4];
            uint2 u1 = *(const uint2*)&support[(size_t)(r1.x & 0xFFFF) * FOUT + fl * 4];
            uint2 u2 = *(const uint2*)&support[(size_t)(r2.x & 0xFFFF) * FOUT + fl * 4];
            uint2 u3 = *(const uint2*)&support[(size_t)(r3.x & 0xFFFF) * FOUT + fl * 4];
            float w0 = __int_as_float(r0.y), w1 = __int_as_float(r1.y);
            float w2 = __int_as_float(r2.y), w3 = __int_as_float(r3.y);
            a0 += bf16_to_f32((ushort)(u0.x & 0xFFFFu)) * w0;
            a1 += bf16_to_f32((ushort)(u0.x >> 16)) * w0;
            a2 += bf16_to_f32((ushort)(u0.y & 0xFFFFu)) * w0;
            a3 += bf16_to_f32((ushort)(u0.y >> 16)) * w0;
            a0 += bf16_to_f32((ushort)(u1.x & 0xFFFFu)) * w1;
            a1 += bf16_to_f32((ushort)(u1.x >> 16)) * w1;
            a2 += bf16_to_f32((ushort)(u1.y & 0xFFFFu)) * w1;
            a3 += bf16_to_f32((ushort)(u1.y >> 16)) * w1;
            a0 += bf16_to_f32((ushort)(u2.x & 0xFFFFu)) * w2;
            a1 += bf16_to_f32((ushort)(u2.x >> 16)) * w2;
            a2 += bf16_to_f32((ushort)(u2.y & 0xFFFFu)) * w2;
            a3 += bf16_to_f32((ushort)(u2.y >> 16)) * w2;
            a0 += bf16_to_f32((ushort)(u3.x & 0xFFFFu)) * w3;
            a1 += bf16_to_f32((ushort)(u3.x >> 16)) * w3;
            a2 += bf16_to_f32((ushort)(u3.y & 0xFFFFu)) * w3;
            a3 += bf16_to_f32((ushort)(u3.y >> 16)) * w3;
        }
        for (; i < re; ++i) {
            int2 r = sorted[i];
            uint2 u = *(const uint2*)&support[(size_t)(r.x & 0xFFFF) * FOUT + fl * 4];
            float wg = __int_as_float(r.y);
            a0 += bf16_to_f32((ushort)(u.x & 0xFFFFu)) * wg;
            a1 += bf16_to_f32((ushort)(u.x >> 16)) * wg;
            a2 += bf16_to_f32((ushort)(u.y & 0xFFFFu)) * wg;
            a3 += bf16_to_f32((ushort)(u.y >> 16)) * wg;
        }
        const int node = node0 + nl;
        if (node < N) {
            float4 o;
            o.x = a0 + bv4.x; o.y = a1 + bv4.y;
            o.z = a2 + bv4.z; o.w = a3 + bv4.w;
            *(float4*)&out[(size_t)node * FOUT + fl * 4] = o;
        }
    }

    // overflow tail: never taken at this size; kept for correctness.
    __syncthreads();
    if (tid == 0) novs = *ovfc;
    __syncthreads();
    int nov = novs;
    if (nov > 0) {
        if (nov > E) nov = E;
        __threadfence();
        for (int k = w; k < nov; k += 4) {
            int4 r = ovf[k];
            if (r.z == B) {
                int node = node0 + ((r.x >> 16) & (NPB - 1));
                if (node < N) {
                    float v = bf16_to_f32(
                        support[(size_t)(r.x & 0xFFFF) * FOUT + lane]);
                    atomicAdd(&out[(size_t)node * FOUT + lane],
                              v * __int_as_float(r.y));
                }
            }
        }
    }
}

extern "C" void kernel_launch(void* const* d_in, const int* in_sizes, int n_in,
                              void* d_out, int out_size, void* d_ws, size_t ws_size,
                              hipStream_t stream) {
    const float* x    = (const float*)d_in[0];
    const float* t    = (const float*)d_in[1];
    const int*   src  = (const int*)d_in[2];
    const int*   dst  = (const int*)d_in[3];
    const float* ev   = (const float*)d_in[4];
    const float* W    = (const float*)d_in[5];
    const float* bias = (const float*)d_in[6];
    float* out = (float*)d_out;

    const int N = in_sizes[1];   // 50000
    const int E = in_sizes[2];   // 800000

    char*   ws      = (char*)d_ws;
    ushort* support = (ushort*)ws;
    int*    cur     = (int*)(ws + OFF_CUR);
    int*    ovfc    = (int*)(ws + OFF_OVFC);
    int2*   tmp     = (int2*)(ws + OFF_TMP);
    int4*   ovf     = (int4*)(ws + OFF_OVF);

    const int GB   = (N + TILE_ROWS - 1) / TILE_ROWS;       // 782
    const int SBP  = (E + EPB - 1) / EPB;                   // 391
    const int NBUK = (N + NPB - 1) / NPB;                   // 1563

    // zero bucket cursors + overflow count (6.5 KB, graph-capturable)
    hipMemsetAsync(ws + OFF_CUR, 0, OFF_TMP - OFF_CUR, stream);

    // 1) fused independent branches: MFMA gemm || bucket-region scatter
    gemm_scatter_kernel<<<GB + SBP, 256, 0, stream>>>(
        x, t, W, support, N, src, dst, ev, cur, tmp, ovfc, ovf,
        E, SBP, NBUK, GB);

    // 2) per-bucket sort + group-per-node walk -> out (+bias)
    bucket_gather_kernel<<<NBUK, 256, 0, stream>>>(
        cur, tmp, support, bias, out, ovfc, ovf, E, N, NBUK);
}